// Round 8
// baseline (371.556 us; speedup 1.0000x reference)
//
#include <hip/hip_runtime.h>

// VectorQuantizer: z (65536 x 512 f32), codebook (16 x 512 f32)
// out = [z_q (65536*512 f32)] [indices as f32 (65536)] [vq_loss (1)]
//
// Numerics (verified round 3, DO NOT change): A=|z|^2, B=z.c, C=|c|^2 exactly
// in f64, round each to f32, then replicate the reference's f32 op sequence
// d = fl32(fl32(A - 2B) + C), argmin with first-index tie-break.
//
// Perf history:
//  r3: 1068 us - double p[16] spill, 2.8 GB HBM.
//  r5: 719 us  - full unroll hoisted loads, VGPR=256 + spill, 1.18 GB.
//  r6: 172 us  - unroll 1, VGPR=52, but traffic 2x ideal (store RFO +
//      poison interplay), occupancy 41% (LDS 33280 -> 4 blocks/CU),
//      VALUBusy 24% -> latency-bound.
//  r7 (this): nontemporal z loads + zq stores (kill RFO / L2 pollution),
//      LDS exactly 32768 (cnorm via per-wave shuffles, loss via per-wave
//      atomics) -> 5 blocks/CU, unroll 2 for 2x LDS-read ILP,
//      __launch_bounds__(256,5) caps VGPR at 102.

typedef float f32x4 __attribute__((ext_vector_type(4)));

constexpr int D      = 512;
constexpr int D4     = D / 4;      // 128 float4 per row
constexpr int K      = 16;
constexpr int BLOCK  = 256;
constexpr int ROWS_PER_BLOCK = 16; // 4 waves x 4 rows
constexpr int GRID   = 2048;

__global__ void __launch_bounds__(BLOCK, 5) vq_kernel(
    const float* __restrict__ z, const float* __restrict__ cb,
    float* __restrict__ zq, float* __restrict__ idx_out,
    float* __restrict__ loss_out, int n_rows, float loss_scale)
{
    __shared__ f32x4 cb_lds4[K * D4];      // exactly 32768 B -> 5 blocks/CU

    const int tid  = threadIdx.x;
    const int lane = tid & 63;
    const int wave = tid >> 6;
    const int sub  = lane >> 4;            // which of the wave's 4 rows
    const int sl   = lane & 15;            // column-group within row

    // ---- stage codebook in LDS (coalesced float4; cached - it's reused) ----
    const f32x4* cb4 = reinterpret_cast<const f32x4*>(cb);
    #pragma unroll
    for (int i = 0; i < (K * D4) / BLOCK; ++i)           // 8 iters
        cb_lds4[i * BLOCK + tid] = cb4[i * BLOCK + tid];
    __syncthreads();

    // ---- per-wave code norms in f64, distributed via shuffles (no LDS) ----
    // lane l: code k_ = l>>2, slice s_ = l&3 (128 elements each)
    float cn[4];
    {
        const int k_ = lane >> 2;
        const int s_ = lane & 3;
        double nacc = 0.0;
        #pragma unroll 1
        for (int j = 0; j < 32; ++j) {
            const int jj = (j + 2 * k_) & 31;            // stagger banks
            f32x4 c = cb_lds4[k_ * D4 + jj * 4 + s_];
            nacc += (double)c[0] * (double)c[0] + (double)c[1] * (double)c[1]
                  + (double)c[2] * (double)c[2] + (double)c[3] * (double)c[3];
        }
        nacc += __shfl_xor(nacc, 1, 64);
        nacc += __shfl_xor(nacc, 2, 64);                 // quad now has full norm
        const float normf = (float)nacc;                 // f32-rounded C
        const int base_k = sl & 3;
        #pragma unroll
        for (int c = 0; c < 4; ++c)
            cn[c] = __shfl(normf, (4 * c + base_k) * 4, 64);
    }
    const int base_k = sl & 3;

    const f32x4* z4  = reinterpret_cast<const f32x4*>(z);
    f32x4*       zq4 = reinterpret_cast<f32x4*>(zq);

    float lp = 0.f;   // loss partial

    const int n_tiles = n_rows / ROWS_PER_BLOCK;
    for (int tile = blockIdx.x; tile < n_tiles; tile += GRID) {
        const int row = tile * ROWS_PER_BLOCK + wave * 4 + sub;
        const long long rb = (long long)row * D4;

        // ---- load this lane's 32 z elements (8 x float4, nontemporal) ----
        f32x4 zr[8];
        #pragma unroll
        for (int i = 0; i < 8; ++i)
            zr[i] = __builtin_nontemporal_load(&z4[rb + i * 16 + sl]);

        // ---- A = |z|^2 in f64: per-lane partial + 16-lane all-reduce ----
        double A = 0.0;
        #pragma unroll
        for (int i = 0; i < 8; ++i) {
            A += (double)zr[i][0] * (double)zr[i][0] + (double)zr[i][1] * (double)zr[i][1]
               + (double)zr[i][2] * (double)zr[i][2] + (double)zr[i][3] * (double)zr[i][3];
        }
        #pragma unroll
        for (int m = 1; m < 16; m <<= 1)
            A += __shfl_xor(A, m, 64);
        const float A32 = (float)A;

        // ---- B = z . c_k in f64, 4 codes per chunk; unroll 2 for LDS ILP ----
        float B32[4];
        #pragma unroll
        for (int c = 0; c < 4; ++c) {
            double a0 = 0.0, a1 = 0.0, a2 = 0.0, a3 = 0.0;
            #pragma unroll 2
            for (int i = 0; i < 8; ++i) {
                const int    idx = (4 * c) * D4 + i * 16 + sl;
                const double zx = (double)zr[i][0], zy = (double)zr[i][1];
                const double zz = (double)zr[i][2], zw = (double)zr[i][3];
                f32x4 c0 = cb_lds4[idx];
                f32x4 c1 = cb_lds4[idx + D4];
                f32x4 c2 = cb_lds4[idx + 2 * D4];
                f32x4 c3 = cb_lds4[idx + 3 * D4];
                a0 = fma((double)c0[0], zx, fma((double)c0[1], zy, fma((double)c0[2], zz, fma((double)c0[3], zw, a0))));
                a1 = fma((double)c1[0], zx, fma((double)c1[1], zy, fma((double)c1[2], zz, fma((double)c1[3], zw, a1))));
                a2 = fma((double)c2[0], zx, fma((double)c2[1], zy, fma((double)c2[2], zz, fma((double)c2[3], zw, a2))));
                a3 = fma((double)c3[0], zx, fma((double)c3[1], zy, fma((double)c3[2], zz, fma((double)c3[3], zw, a3))));
            }
            // reduce-scatter over lane bits 0,1: lane keeps code 4c + (lane&3)
            {
                const int mb0 = lane & 1;
                double s0 = mb0 ? a0 : a1;
                double s1 = mb0 ? a2 : a3;
                double r0 = __shfl_xor(s0, 1, 64);
                double r1 = __shfl_xor(s1, 1, 64);
                double t0 = (mb0 ? a1 : a0) + r0;
                double t1 = (mb0 ? a3 : a2) + r1;
                const int mb1 = (lane >> 1) & 1;
                double s2 = mb1 ? t0 : t1;
                double r2 = __shfl_xor(s2, 2, 64);
                double u  = (mb1 ? t1 : t0) + r2;
                // complete the row sum over lane bits 2,3 (all-reduce)
                u += __shfl_xor(u, 4, 64);
                u += __shfl_xor(u, 8, 64);
                B32[c] = (float)u;
            }
        }

        // ---- reference's f32 distance sequence + argmin (first-index ties) ----
        float bd = (A32 - 2.0f * B32[0]) + cn[0];
        int   bk = base_k;
        #pragma unroll
        for (int c = 1; c < 4; ++c) {
            float d = (A32 - 2.0f * B32[c]) + cn[c];
            if (d < bd) { bd = d; bk = 4 * c + base_k; }   // strict < keeps lowest code
        }
        #pragma unroll
        for (int b = 0; b < 2; ++b) {                      // codes replicated over bits 2,3
            float od = __shfl_xor(bd, 1 << b, 64);
            int   ok = __shfl_xor(bk, 1 << b, 64);
            if (od < bd || (od == bd && ok < bk)) { bd = od; bk = ok; }
        }
        if (sl == 0) idx_out[row] = (float)bk;

        // ---- gather codebook row -> z_q (nontemporal store), loss (f32) ----
        #pragma unroll
        for (int i = 0; i < 8; ++i) {
            f32x4 c = cb_lds4[bk * D4 + i * 16 + sl];
            __builtin_nontemporal_store(c, &zq4[rb + i * 16 + sl]);
            float dx = zr[i][0] - c[0], dy = zr[i][1] - c[1];
            float dz = zr[i][2] - c[2], dw = zr[i][3] - c[3];
            lp += dx * dx + dy * dy + dz * dz + dw * dw;
        }
    }

    // ---- loss: wave butterfly -> one atomic per wave (no LDS needed) ----
    #pragma unroll
    for (int m = 1; m < 64; m <<= 1)
        lp += __shfl_xor(lp, m, 64);
    if (lane == 0)
        atomicAdd(loss_out, lp * loss_scale);
}

extern "C" void kernel_launch(void* const* d_in, const int* in_sizes, int n_in,
                              void* d_out, int out_size, void* d_ws, size_t ws_size,
                              hipStream_t stream) {
    const float* z  = (const float*)d_in[0];
    const float* cb = (const float*)d_in[1];

    const int n_elems = in_sizes[0];        // 33554432
    const int n_rows  = n_elems / D;        // 65536

    float* zq   = (float*)d_out;
    float* idx  = zq + n_elems;
    float* loss = idx + n_rows;

    // loss element is atomically accumulated -> must start at 0 (d_out is poisoned)
    hipMemsetAsync((void*)loss, 0, sizeof(float), stream);

    const float loss_scale = 1.25f / (float)n_elems;
    vq_kernel<<<GRID, BLOCK, 0, stream>>>(z, cb, zq, idx, loss, n_rows, loss_scale);
}

// Round 9
// 316.459 us; speedup vs baseline: 1.1741x; 1.1741x over previous
//
#include <hip/hip_runtime.h>

// VectorQuantizer: z (65536 x 512 f32), codebook (16 x 512 f32)
// out = [z_q (65536*512 f32)] [indices as f32 (65536)] [vq_loss (1)]
//
// Numerics (verified round 3, DO NOT change): A=|z|^2, B=z.c, C=|c|^2 exactly
// in f64, round each to f32, then replicate the reference's f32 op sequence
// d = fl32(fl32(A - 2B) + C), argmin with first-index tie-break.
//
// Perf history:
//  r3: 1068 us - double p[16] spill, 2.8 GB HBM.
//  r5: 719 us  - full-unroll hoisting, VGPR=256 + spill, 1.18 GB.
//  r6: 172 us  - unroll 1, VGPR=52, 0.53 GB (134 MB of it = poison-eviction
//      contamination in the profiled window), VALUBusy 24% -> latency-bound.
//  r8: 203 us  - REGRESSION: nontemporal loads/stores raised WRITE 262->308MB
//      and lost L2 assist; occupancy unchanged -> reverted here.
//  r9 (this): plain loads/stores; n_tiles = 2*GRID exactly, so each block
//      owns 2 tiles -> issue BOTH tiles' z loads up front (64 VGPRs in
//      flight), compute tile0 then tile1: tile1's HBM latency hides under
//      tile0's f64 compute. __launch_bounds__(256,4).

typedef float f32x4 __attribute__((ext_vector_type(4)));

constexpr int D      = 512;
constexpr int D4     = D / 4;      // 128 float4 per row
constexpr int K      = 16;
constexpr int BLOCK  = 256;
constexpr int ROWS_PER_BLOCK = 16; // 4 waves x 4 rows
constexpr int GRID   = 2048;

__device__ __forceinline__ void process_tile(
    int row, int lane, int sl, int base_k,
    const f32x4* __restrict__ cb_lds4, const float cn[4],
    const f32x4 (&zr)[8], f32x4* __restrict__ zq4,
    float* __restrict__ idx_out, float& lp)
{
    const long long rb = (long long)row * D4;

    // ---- A = |z|^2 in f64: per-lane partial + 16-lane all-reduce ----
    double A = 0.0;
    #pragma unroll
    for (int i = 0; i < 8; ++i) {
        A += (double)zr[i][0] * (double)zr[i][0] + (double)zr[i][1] * (double)zr[i][1]
           + (double)zr[i][2] * (double)zr[i][2] + (double)zr[i][3] * (double)zr[i][3];
    }
    #pragma unroll
    for (int m = 1; m < 16; m <<= 1)
        A += __shfl_xor(A, m, 64);
    const float A32 = (float)A;

    // ---- B = z . c_k in f64, 4 codes per chunk; unroll 2 for LDS ILP ----
    float B32[4];
    #pragma unroll
    for (int c = 0; c < 4; ++c) {
        double a0 = 0.0, a1 = 0.0, a2 = 0.0, a3 = 0.0;
        #pragma unroll 2
        for (int i = 0; i < 8; ++i) {
            const int    idx = (4 * c) * D4 + i * 16 + sl;
            const double zx = (double)zr[i][0], zy = (double)zr[i][1];
            const double zz = (double)zr[i][2], zw = (double)zr[i][3];
            f32x4 c0 = cb_lds4[idx];
            f32x4 c1 = cb_lds4[idx + D4];
            f32x4 c2 = cb_lds4[idx + 2 * D4];
            f32x4 c3 = cb_lds4[idx + 3 * D4];
            a0 = fma((double)c0[0], zx, fma((double)c0[1], zy, fma((double)c0[2], zz, fma((double)c0[3], zw, a0))));
            a1 = fma((double)c1[0], zx, fma((double)c1[1], zy, fma((double)c1[2], zz, fma((double)c1[3], zw, a1))));
            a2 = fma((double)c2[0], zx, fma((double)c2[1], zy, fma((double)c2[2], zz, fma((double)c2[3], zw, a2))));
            a3 = fma((double)c3[0], zx, fma((double)c3[1], zy, fma((double)c3[2], zz, fma((double)c3[3], zw, a3))));
        }
        // reduce-scatter over lane bits 0,1: lane keeps code 4c + (lane&3)
        const int mb0 = lane & 1;
        double s0 = mb0 ? a0 : a1;
        double s1 = mb0 ? a2 : a3;
        double r0 = __shfl_xor(s0, 1, 64);
        double r1 = __shfl_xor(s1, 1, 64);
        double t0 = (mb0 ? a1 : a0) + r0;
        double t1 = (mb0 ? a3 : a2) + r1;
        const int mb1 = (lane >> 1) & 1;
        double s2 = mb1 ? t0 : t1;
        double r2 = __shfl_xor(s2, 2, 64);
        double u  = (mb1 ? t1 : t0) + r2;
        // complete the row sum over lane bits 2,3 (all-reduce)
        u += __shfl_xor(u, 4, 64);
        u += __shfl_xor(u, 8, 64);
        B32[c] = (float)u;
    }

    // ---- reference's f32 distance sequence + argmin (first-index ties) ----
    float bd = (A32 - 2.0f * B32[0]) + cn[0];
    int   bk = base_k;
    #pragma unroll
    for (int c = 1; c < 4; ++c) {
        float d = (A32 - 2.0f * B32[c]) + cn[c];
        if (d < bd) { bd = d; bk = 4 * c + base_k; }   // strict < keeps lowest code
    }
    #pragma unroll
    for (int b = 0; b < 2; ++b) {                      // codes replicated over bits 2,3
        float od = __shfl_xor(bd, 1 << b, 64);
        int   ok = __shfl_xor(bk, 1 << b, 64);
        if (od < bd || (od == bd && ok < bk)) { bd = od; bk = ok; }
    }
    if (sl == 0) idx_out[row] = (float)bk;

    // ---- gather codebook row -> z_q, accumulate loss (f32) ----
    #pragma unroll
    for (int i = 0; i < 8; ++i) {
        f32x4 c = cb_lds4[bk * D4 + i * 16 + sl];
        zq4[rb + i * 16 + sl] = c;
        float dx = zr[i][0] - c[0], dy = zr[i][1] - c[1];
        float dz = zr[i][2] - c[2], dw = zr[i][3] - c[3];
        lp += dx * dx + dy * dy + dz * dz + dw * dw;
    }
}

__global__ void __launch_bounds__(BLOCK, 4) vq_kernel(
    const float* __restrict__ z, const float* __restrict__ cb,
    float* __restrict__ zq, float* __restrict__ idx_out,
    float* __restrict__ loss_out, int n_rows, float loss_scale)
{
    __shared__ f32x4 cb_lds4[K * D4];      // exactly 32768 B

    const int tid  = threadIdx.x;
    const int lane = tid & 63;
    const int wave = tid >> 6;
    const int sub  = lane >> 4;            // which of the wave's 4 rows
    const int sl   = lane & 15;            // column-group within row
    const int base_k = sl & 3;

    // ---- stage codebook in LDS (coalesced float4) ----
    const f32x4* cb4 = reinterpret_cast<const f32x4*>(cb);
    #pragma unroll
    for (int i = 0; i < (K * D4) / BLOCK; ++i)           // 8 iters
        cb_lds4[i * BLOCK + tid] = cb4[i * BLOCK + tid];
    __syncthreads();

    // ---- per-wave code norms in f64, distributed via shuffles (no LDS) ----
    // lane l: code k_ = l>>2, slice s_ = l&3 (128 elements each)
    float cn[4];
    {
        const int k_ = lane >> 2;
        const int s_ = lane & 3;
        double nacc = 0.0;
        #pragma unroll 1
        for (int j = 0; j < 32; ++j) {
            f32x4 c = cb_lds4[k_ * D4 + j * 4 + s_];
            nacc += (double)c[0] * (double)c[0] + (double)c[1] * (double)c[1]
                  + (double)c[2] * (double)c[2] + (double)c[3] * (double)c[3];
        }
        nacc += __shfl_xor(nacc, 1, 64);
        nacc += __shfl_xor(nacc, 2, 64);                 // quad now has full norm
        const float normf = (float)nacc;                 // f32-rounded C
        #pragma unroll
        for (int c = 0; c < 4; ++c)
            cn[c] = __shfl(normf, (4 * c + base_k) * 4, 64);
    }

    const f32x4* z4  = reinterpret_cast<const f32x4*>(z);
    f32x4*       zq4 = reinterpret_cast<f32x4*>(zq);

    float lp = 0.f;   // loss partial

    const int n_tiles = n_rows / ROWS_PER_BLOCK;         // 4096 = 2 * GRID
    const int t0 = blockIdx.x;
    const int t1 = blockIdx.x + GRID;

    // ---- issue BOTH tiles' z loads up front: t1's latency hides under
    //      t0's f64 compute phase ----
    const int  row0  = t0 * ROWS_PER_BLOCK + wave * 4 + sub;
    const bool has1  = (t1 < n_tiles);
    const int  row1  = has1 ? (t1 * ROWS_PER_BLOCK + wave * 4 + sub) : row0;

    f32x4 zr0[8], zr1[8];
    {
        const long long rb0 = (long long)row0 * D4;
        #pragma unroll
        for (int i = 0; i < 8; ++i)
            zr0[i] = z4[rb0 + i * 16 + sl];
        const long long rb1 = (long long)row1 * D4;
        #pragma unroll
        for (int i = 0; i < 8; ++i)
            zr1[i] = z4[rb1 + i * 16 + sl];
    }

    if (t0 < n_tiles)
        process_tile(row0, lane, sl, base_k, cb_lds4, cn, zr0, zq4, idx_out, lp);
    if (has1)
        process_tile(row1, lane, sl, base_k, cb_lds4, cn, zr1, zq4, idx_out, lp);

    // ---- loss: wave butterfly -> one atomic per wave ----
    #pragma unroll
    for (int m = 1; m < 64; m <<= 1)
        lp += __shfl_xor(lp, m, 64);
    if (lane == 0)
        atomicAdd(loss_out, lp * loss_scale);
}

extern "C" void kernel_launch(void* const* d_in, const int* in_sizes, int n_in,
                              void* d_out, int out_size, void* d_ws, size_t ws_size,
                              hipStream_t stream) {
    const float* z  = (const float*)d_in[0];
    const float* cb = (const float*)d_in[1];

    const int n_elems = in_sizes[0];        // 33554432
    const int n_rows  = n_elems / D;        // 65536

    float* zq   = (float*)d_out;
    float* idx  = zq + n_elems;
    float* loss = idx + n_rows;

    // loss element is atomically accumulated -> must start at 0 (d_out is poisoned)
    hipMemsetAsync((void*)loss, 0, sizeof(float), stream);

    const float loss_scale = 1.25f / (float)n_elems;
    vq_kernel<<<GRID, BLOCK, 0, stream>>>(z, cb, zq, idx, loss, n_rows, loss_scale);
}